// Round 7
// baseline (72.372 us; speedup 1.0000x reference)
//
#include <hip/hip_runtime.h>

// AUAvULoss: probs[N,8], y[N,8] one-hot, weights[N,8] -> (avu_loss, CE_loss)
//
// *** ROUND 7 = DIAGNOSTIC ROUND ***
// pass1 sweeps the inputs TWICE (rep loop) so its dispatch exceeds the ~39us
// harness fill kernels and surfaces in the rocprof top-5 with real counters
// (dur, FETCH_SIZE, VALUBusy). Correctness preserved: min/max & stash writes
// are idempotent; focal/CE sums are halved after the doubled accumulation
// (fp error ~1e-7, threshold 5e-2). Decides: L3-resident (FETCH<<96MB) vs
// HBM-read-limited (FETCH~190MB @ ~3TB/s) vs VALU-bound (VALUBusy>50%).
//
// Pipeline otherwise identical to R4/R6 (58us baseline): 3 kernels, no
// grid.sync (R3: cross-XCD fence disaster, 426us), no global atomics.

constexpr int C     = 8;
constexpr int NTH   = 21;
constexpr int NB    = 22;     // 0..20 = first threshold satisfied; 21 = none
constexpr int NREPS = 2;      // DIAGNOSTIC: sweep inputs twice
constexpr int NBLK1 = 2048;
constexpr int BS1   = 256;
constexpr int NBLK2 = 512;
constexpr int BS2   = 512;
constexpr int NREP  = 32;     // LDS hist replicas
constexpr int RSTR  = 89;     // replica stride (odd -> distinct banks)
constexpr float LOG_FEPS = -18.420680743952367f;  // logf(1e-8f)

struct Accum {
  int   l0;
  float f_part[NBLK1], c_part[NBLK1], mn_part[NBLK1], mx_part[NBLK1];
};

template <bool STASH>
__global__ __launch_bounds__(BS1) void pass1x2_k(const float4* __restrict__ p4,
                                                 const float4* __restrict__ y4,
                                                 const float4* __restrict__ w4,
                                                 const float*  __restrict__ yraw,
                                                 Accum* __restrict__ acc,
                                                 float2* __restrict__ stash, int N) {
  __shared__ int sh_l0;
  if (threadIdx.x == 0) {
    float best = yraw[0]; int bi = 0;
#pragma unroll
    for (int j = 1; j < C; ++j) { if (yraw[j] > best) { best = yraw[j]; bi = j; } }
    sh_l0 = bi;
    if (blockIdx.x == 0) acc->l0 = bi;
  }
  __syncthreads();
  const int l0   = sh_l0;
  const int q    = threadIdx.x & 1;          // channel half (0: ch0-3, 1: ch4-7)
  const int T    = blockIdx.x * BS1 + threadIdx.x;
  const int S    = NBLK1 * BS1;
  const int twoN = 2 * N;                    // f4s per array (even; pairs intact)

  float fsum = 0.f, csum = 0.f;
  float umin = __uint_as_float(0x7F800000u), umax = 0.f;

  for (int rep = 0; rep < NREPS; ++rep) {    // DIAGNOSTIC double sweep
    for (int idx = T; idx < twoN; idx += S) {
      float4 pv = p4[idx];
      float4 yv = y4[idx];
      float4 wv = w4[idx];
      float P[4] = {pv.x, pv.y, pv.z, pv.w};
      float Y[4] = {yv.x, yv.y, yv.z, yv.w};
      float W[4] = {wv.x, wv.y, wv.z, wv.w};
      float up = 0.f, cep = 0.f, fop = 0.f;
      float cmax = P[0]; int pid = 0;
#pragma unroll
      for (int j = 0; j < 4; ++j) {
        if (j > 0 && P[j] > cmax) { cmax = P[j]; pid = j; }  // first-occurrence
        float le = __logf(fmaxf(P[j], 1e-10f));              // entropy log (EPS=1e-10)
        up -= P[j] * le;
        float lf = fmaxf(le, LOG_FEPS);                      // = log(max(p,1e-8))
        float t  = Y[j] * lf;
        cep -= t; fop -= t * W[j];
      }
      pid += 4 * q;
      fsum += fop; csum += cep;              // each lane adds its own half
      float unc = up + __shfl_xor(up, 1);
      float oc  = __shfl_xor(cmax, 1);
      int   op  = __shfl_xor(pid, 1);
      float lo_c = q ? oc : cmax;  int lo_p = q ? op : pid;
      float hi_c = q ? cmax : oc;  int hi_p = q ? pid : op;
      float conf = (hi_c > lo_c) ? hi_c : lo_c;   // ties -> low half (first occ.)
      int   pred = (hi_c > lo_c) ? hi_p : lo_p;
      umin = fminf(umin, unc); umax = fmaxf(umax, unc);
      if (STASH && q == 0)                   // idempotent across reps
        stash[idx >> 1] = make_float2(unc, (pred == l0) ? conf : -conf);
    }
  }
  fsum *= (1.0f / NREPS);                    // undo the doubled accumulation
  csum *= (1.0f / NREPS);

  float v0 = fsum, v1 = csum, v2 = umin, v3 = umax;
#pragma unroll
  for (int o = 32; o > 0; o >>= 1) {
    v0 += __shfl_down(v0, o); v1 += __shfl_down(v1, o);
    v2 = fminf(v2, __shfl_down(v2, o)); v3 = fmaxf(v3, __shfl_down(v3, o));
  }
  __shared__ float r0[4], r1[4], r2[4], r3[4];
  int ln = threadIdx.x & 63, wd = threadIdx.x >> 6;
  if (ln == 0) { r0[wd] = v0; r1[wd] = v1; r2[wd] = v2; r3[wd] = v3; }
  __syncthreads();
  if (threadIdx.x == 0) {
    acc->f_part[blockIdx.x]  = r0[0] + r0[1] + r0[2] + r0[3];
    acc->c_part[blockIdx.x]  = r1[0] + r1[1] + r1[2] + r1[3];
    acc->mn_part[blockIdx.x] = fminf(fminf(r2[0], r2[1]), fminf(r2[2], r2[3]));
    acc->mx_part[blockIdx.x] = fmaxf(fmaxf(r3[0], r3[1]), fmaxf(r3[2], r3[3]));
  }
}

// Redundant per-block umin/umax reduction (no extra kernel launch).
__device__ __forceinline__ void reduce_minmax(const Accum* __restrict__ acc,
                                              float& out_umin, float& out_scale) {
  __shared__ float rmn[BS2 / 64], rmx[BS2 / 64];
  __shared__ float sh_umin, sh_umax;
  float mn = __uint_as_float(0x7F800000u), mx = 0.f;
  for (int i = threadIdx.x; i < NBLK1; i += BS2) {
    mn = fminf(mn, acc->mn_part[i]);
    mx = fmaxf(mx, acc->mx_part[i]);
  }
#pragma unroll
  for (int o = 32; o > 0; o >>= 1) {
    mn = fminf(mn, __shfl_down(mn, o));
    mx = fmaxf(mx, __shfl_down(mx, o));
  }
  int lane = threadIdx.x & 63, wid = threadIdx.x >> 6;
  if (lane == 0) { rmn[wid] = mn; rmx[wid] = mx; }
  __syncthreads();
  if (threadIdx.x == 0) {
    float a = rmn[0], b = rmx[0];
#pragma unroll
    for (int wv = 1; wv < BS2 / 64; ++wv) { a = fminf(a, rmn[wv]); b = fmaxf(b, rmx[wv]); }
    sh_umin = a; sh_umax = b;
  }
  __syncthreads();
  out_umin = sh_umin; out_scale = sh_umax - sh_umin;
}

__device__ __forceinline__ void hist_update(float* hb, float unc, float cval,
                                            float umin, float scale) {
  float tu = tanhf(unc);
  int t0 = NB - 1;
  for (int t = 0; t < NTH; ++t) {
    float thr = umin + ((float)t * 0.05f) * scale;  // same expr as reference
    if (unc <= thr) { t0 = t; break; }
  }
  bool  corr = cval > 0.f;
  float conf = fabsf(cval);
  float base = corr ? conf : (1.f - conf);
  int   row  = corr ? 0 : 2;
  atomicAdd(&hb[row * NB + t0],       base * (1.f - tu));
  atomicAdd(&hb[(row + 1) * NB + t0], base * tu);
}

__global__ __launch_bounds__(BS2) void pass2_k(const float2* __restrict__ stash,
                                               const Accum* __restrict__ acc,
                                               float* __restrict__ partial2, int N) {
  __shared__ float h[NREP * RSTR];
  for (int k = threadIdx.x; k < NREP * RSTR; k += BS2) h[k] = 0.f;
  float umin, scale;
  reduce_minmax(acc, umin, scale);   // contains __syncthreads (covers h init)
  float* hb = &h[(threadIdx.x & (NREP - 1)) * RSTR];
  int stride = gridDim.x * blockDim.x;
  for (int i = blockIdx.x * blockDim.x + threadIdx.x; i < N; i += stride) {
    float2 s = stash[i];
    hist_update(hb, s.x, s.y, umin, scale);
  }
  __syncthreads();
  for (int idx = threadIdx.x; idx < 4 * NB; idx += BS2) {
    float s = 0.f;
#pragma unroll
    for (int r = 0; r < NREP; ++r) s += h[r * RSTR + idx];
    partial2[idx * NBLK2 + blockIdx.x] = s;
  }
}

// Fallback: no stash space -> re-read probs, recompute conf/pred/unc.
__global__ __launch_bounds__(BS2) void pass2f_k(const float4* __restrict__ p4,
                                                const Accum* __restrict__ acc,
                                                float* __restrict__ partial2, int N) {
  __shared__ float h[NREP * RSTR];
  for (int k = threadIdx.x; k < NREP * RSTR; k += BS2) h[k] = 0.f;
  float umin, scale;
  reduce_minmax(acc, umin, scale);
  const int l0 = acc->l0;
  float* hb = &h[(threadIdx.x & (NREP - 1)) * RSTR];
  int stride = gridDim.x * blockDim.x;
  for (int i = blockIdx.x * blockDim.x + threadIdx.x; i < N; i += stride) {
    float4 a = p4[2 * i], b = p4[2 * i + 1];
    float p[8] = {a.x, a.y, a.z, a.w, b.x, b.y, b.z, b.w};
    float conf = p[0]; int pred = 0;
    float unc = 0.f;
#pragma unroll
    for (int j = 0; j < 8; ++j) {
      if (p[j] > conf) { conf = p[j]; pred = j; }
      unc -= p[j] * __logf(fmaxf(p[j], 1e-10f));
    }
    hist_update(hb, unc, (pred == l0) ? conf : -conf, umin, scale);
  }
  __syncthreads();
  for (int idx = threadIdx.x; idx < 4 * NB; idx += BS2) {
    float s = 0.f;
#pragma unroll
    for (int r = 0; r < NREP; ++r) s += h[r * RSTR + idx];
    partial2[idx * NBLK2 + blockIdx.x] = s;
  }
}

__global__ __launch_bounds__(1024) void final_k(const float* __restrict__ partial2,
                                                const Accum* __restrict__ acc,
                                                float* __restrict__ out, int N) {
  __shared__ float hist[4 * NB];
  __shared__ double df[16], dc[16];
  __shared__ float sh_f, sh_c;
  int lane = threadIdx.x & 63, wid = threadIdx.x >> 6;  // 16 waves

  double f = 0.0, c = 0.0;
  for (int i = threadIdx.x; i < NBLK1; i += 1024) {
    f += (double)acc->f_part[i]; c += (double)acc->c_part[i];
  }
#pragma unroll
  for (int o = 32; o > 0; o >>= 1) { f += __shfl_down(f, o); c += __shfl_down(c, o); }
  if (lane == 0) { df[wid] = f; dc[wid] = c; }

  for (int cidx = wid; cidx < 4 * NB; cidx += 16) {
    float s = 0.f;
    for (int k = lane; k < NBLK2; k += 64) s += partial2[cidx * NBLK2 + k];
#pragma unroll
    for (int o = 32; o > 0; o >>= 1) s += __shfl_down(s, o);
    if (lane == 0) hist[cidx] = s;
  }
  __syncthreads();
  if (threadIdx.x == 0) {
    double ft = 0.0, ct = 0.0;
#pragma unroll
    for (int wv = 0; wv < 16; ++wv) { ft += df[wv]; ct += dc[wv]; }
    sh_f = (float)ft; sh_c = (float)ct;

    const float *hac = &hist[0], *hau = &hist[NB], *hic = &hist[2 * NB], *hiu = &hist[3 * NB];
    float tot_au = 0.f, tot_iu = 0.f;
    for (int s = 0; s < NB; ++s) { tot_au += hau[s]; tot_iu += hiu[s]; }
    float pac = 0.f, pau = 0.f, pic = 0.f, piu = 0.f, auc = 0.f, prev = 0.f;
    for (int t = 0; t < NTH; ++t) {
      pac += hac[t]; pau += hau[t]; pic += hic[t]; piu += hiu[t];
      float n_ac = pac, n_au = tot_au - pau, n_ic = pic, n_iu = tot_iu - piu;
      float avu = (n_ac + n_iu) / (n_ac + n_au + n_ic + n_iu + 1e-10f);
      if (t > 0) auc += 0.5f * (avu + prev) * 0.05f;
      prev = avu;
    }
    out[0] = -logf(auc + 1e-10f) + sh_f / (float)N;  // BETA = 1
    out[1] = sh_c / (float)N;
  }
}

extern "C" void kernel_launch(void* const* d_in, const int* in_sizes, int n_in,
                              void* d_out, int out_size, void* d_ws, size_t ws_size,
                              hipStream_t stream) {
  const float* probs = (const float*)d_in[0];
  const float* y     = (const float*)d_in[1];
  const float* w     = (const float*)d_in[2];
  float* out = (float*)d_out;
  int N = in_sizes[0] / C;

  Accum* acc = (Accum*)d_ws;
  size_t off_p2 = (sizeof(Accum) + 255) & ~(size_t)255;
  size_t off_st = (off_p2 + (size_t)(4 * NB) * NBLK2 * sizeof(float) + 255) & ~(size_t)255;
  size_t need   = off_st + (size_t)N * sizeof(float2);
  float*  partial2 = (float*)((char*)d_ws + off_p2);
  float2* stash    = (float2*)((char*)d_ws + off_st);

  if (ws_size >= need) {
    pass1x2_k<true><<<NBLK1, BS1, 0, stream>>>((const float4*)probs, (const float4*)y,
                                               (const float4*)w, y, acc, stash, N);
    pass2_k<<<NBLK2, BS2, 0, stream>>>(stash, acc, partial2, N);
  } else {
    pass1x2_k<false><<<NBLK1, BS1, 0, stream>>>((const float4*)probs, (const float4*)y,
                                                (const float4*)w, y, acc, nullptr, N);
    pass2f_k<<<NBLK2, BS2, 0, stream>>>((const float4*)probs, acc, partial2, N);
  }
  final_k<<<1, 1024, 0, stream>>>(partial2, acc, out, N);
}

// Round 8
// 58.482 us; speedup vs baseline: 1.2375x; 1.2375x over previous
//
#include <hip/hip_runtime.h>

// AUAvULoss: probs[N,8], y[N,8] one-hot, weights[N,8] -> (avu_loss, CE_loss)
//
// R7 diagnostics: pass1 ~25us @ ~4.2TB/s (FETCH 94MB, VALU 26%), gaps ~1us
// => pass2+final ~30us = the actual sink (never visible in top-5).
// R8: move ALL per-sample transcendentals (tanhf) into pass1 (memory-bound,
// VALU idle); stash SoA (u, +-q1, +-q2) where q1=base*(1-tanh), q2=base*tanh,
// sign bit = correct. pass2 = branchless unrolled 21-threshold scan (no
// divergent break) + 2 LDS atomics per sample. No grid.sync (R3: 426us
// disaster). No global atomics.

constexpr int C     = 8;
constexpr int NTH   = 21;
constexpr int NB    = 22;     // 0..20 = first threshold satisfied; 21 = none
constexpr int NBLK1 = 2048;
constexpr int BS1   = 256;
constexpr int NBLK2 = 512;
constexpr int BS2   = 512;
constexpr int NREP  = 32;     // LDS hist replicas
constexpr int RSTR  = 89;     // replica stride (odd -> distinct banks)
constexpr float LOG_FEPS = -18.420680743952367f;  // logf(1e-8f)

struct Accum {
  int   l0;
  float f_part[NBLK1], c_part[NBLK1], mn_part[NBLK1], mx_part[NBLK1];
};

template <bool STASH>
__global__ __launch_bounds__(BS1) void pass1_k(const float4* __restrict__ p4,
                                               const float4* __restrict__ y4,
                                               const float4* __restrict__ w4,
                                               const float*  __restrict__ yraw,
                                               Accum* __restrict__ acc,
                                               float* __restrict__ su,
                                               float* __restrict__ sq1,
                                               float* __restrict__ sq2, int N) {
  __shared__ int sh_l0;
  if (threadIdx.x == 0) {
    float best = yraw[0]; int bi = 0;
#pragma unroll
    for (int j = 1; j < C; ++j) { if (yraw[j] > best) { best = yraw[j]; bi = j; } }
    sh_l0 = bi;
    if (blockIdx.x == 0) acc->l0 = bi;
  }
  __syncthreads();
  const int l0   = sh_l0;
  const int q    = threadIdx.x & 1;          // channel half (0: ch0-3, 1: ch4-7)
  const int T    = blockIdx.x * BS1 + threadIdx.x;
  const int S    = NBLK1 * BS1;
  const int twoN = 2 * N;                    // f4s per array (even; pairs intact)

  float fsum = 0.f, csum = 0.f;
  float umin = __uint_as_float(0x7F800000u), umax = 0.f;

  for (int idx = T; idx < twoN; idx += S) {
    float4 pv = p4[idx];
    float4 yv = y4[idx];
    float4 wv = w4[idx];
    float P[4] = {pv.x, pv.y, pv.z, pv.w};
    float Y[4] = {yv.x, yv.y, yv.z, yv.w};
    float W[4] = {wv.x, wv.y, wv.z, wv.w};
    float up = 0.f, cep = 0.f, fop = 0.f;
    float cmax = P[0]; int pid = 0;
#pragma unroll
    for (int j = 0; j < 4; ++j) {
      if (j > 0 && P[j] > cmax) { cmax = P[j]; pid = j; }  // first-occurrence
      float le = __logf(fmaxf(P[j], 1e-10f));              // entropy log (EPS=1e-10)
      up -= P[j] * le;
      float lf = fmaxf(le, LOG_FEPS);                      // = log(max(p,1e-8))
      float t  = Y[j] * lf;
      cep -= t; fop -= t * W[j];
    }
    pid += 4 * q;
    fsum += fop; csum += cep;                // each lane adds its own half
    float unc = up + __shfl_xor(up, 1);
    float oc  = __shfl_xor(cmax, 1);
    int   op  = __shfl_xor(pid, 1);
    float lo_c = q ? oc : cmax;  int lo_p = q ? op : pid;
    float hi_c = q ? cmax : oc;  int hi_p = q ? pid : op;
    float conf = (hi_c > lo_c) ? hi_c : lo_c;   // ties -> low half (first occ.)
    int   pred = (hi_c > lo_c) ? hi_p : lo_p;
    umin = fminf(umin, unc); umax = fmaxf(umax, unc);
    if (STASH && q == 0) {                   // even lanes own the sample
      bool  corr = (pred == l0);
      float tu   = tanhf(unc);               // transcendental done HERE (free)
      float base = corr ? conf : (1.f - conf);
      float q1   = base * (1.f - tu);
      float q2   = base * tu;
      int   i    = idx >> 1;
      su[i]  = unc;
      sq1[i] = corr ? q1 : -q1;              // sign bit = !correct (handles -0.0)
      sq2[i] = corr ? q2 : -q2;
    }
  }

  float v0 = fsum, v1 = csum, v2 = umin, v3 = umax;
#pragma unroll
  for (int o = 32; o > 0; o >>= 1) {
    v0 += __shfl_down(v0, o); v1 += __shfl_down(v1, o);
    v2 = fminf(v2, __shfl_down(v2, o)); v3 = fmaxf(v3, __shfl_down(v3, o));
  }
  __shared__ float r0[4], r1[4], r2[4], r3[4];
  int ln = threadIdx.x & 63, wd = threadIdx.x >> 6;
  if (ln == 0) { r0[wd] = v0; r1[wd] = v1; r2[wd] = v2; r3[wd] = v3; }
  __syncthreads();
  if (threadIdx.x == 0) {
    acc->f_part[blockIdx.x]  = r0[0] + r0[1] + r0[2] + r0[3];
    acc->c_part[blockIdx.x]  = r1[0] + r1[1] + r1[2] + r1[3];
    acc->mn_part[blockIdx.x] = fminf(fminf(r2[0], r2[1]), fminf(r2[2], r2[3]));
    acc->mx_part[blockIdx.x] = fmaxf(fmaxf(r3[0], r3[1]), fmaxf(r3[2], r3[3]));
  }
}

// Redundant per-block umin/umax reduction (no extra kernel launch).
__device__ __forceinline__ void reduce_minmax(const Accum* __restrict__ acc,
                                              float& out_umin, float& out_scale) {
  __shared__ float rmn[BS2 / 64], rmx[BS2 / 64];
  __shared__ float sh_umin, sh_umax;
  float mn = __uint_as_float(0x7F800000u), mx = 0.f;
  for (int i = threadIdx.x; i < NBLK1; i += BS2) {
    mn = fminf(mn, acc->mn_part[i]);
    mx = fmaxf(mx, acc->mx_part[i]);
  }
#pragma unroll
  for (int o = 32; o > 0; o >>= 1) {
    mn = fminf(mn, __shfl_down(mn, o));
    mx = fmaxf(mx, __shfl_down(mx, o));
  }
  int lane = threadIdx.x & 63, wid = threadIdx.x >> 6;
  if (lane == 0) { rmn[wid] = mn; rmx[wid] = mx; }
  __syncthreads();
  if (threadIdx.x == 0) {
    float a = rmn[0], b = rmx[0];
#pragma unroll
    for (int wv = 1; wv < BS2 / 64; ++wv) { a = fminf(a, rmn[wv]); b = fmaxf(b, rmx[wv]); }
    sh_umin = a; sh_umax = b;
  }
  __syncthreads();
  out_umin = sh_umin; out_scale = sh_umax - sh_umin;
}

// Branchless first-satisfied-threshold: descending predicated scan.
// thr increasing => smallest satisfying t wins. Bit-identical comparisons
// to the reference expression umin + (t*0.05f)*scale.
__device__ __forceinline__ int bin_of(float u, float umin, float scale) {
  int t0 = NB - 1;
#pragma unroll
  for (int t = NTH - 1; t >= 0; --t) {
    float thr = umin + ((float)t * 0.05f) * scale;
    if (u <= thr) t0 = t;                 // cndmask, no branch
  }
  return t0;
}

__global__ __launch_bounds__(BS2) void pass2_k(const float* __restrict__ su,
                                               const float* __restrict__ sq1,
                                               const float* __restrict__ sq2,
                                               const Accum* __restrict__ acc,
                                               float* __restrict__ partial2, int N) {
  __shared__ float h[NREP * RSTR];
  for (int k = threadIdx.x; k < NREP * RSTR; k += BS2) h[k] = 0.f;
  float umin, scale;
  reduce_minmax(acc, umin, scale);   // contains __syncthreads (covers h init)
  float* hb = &h[(threadIdx.x & (NREP - 1)) * RSTR];
  int stride = gridDim.x * blockDim.x;
  for (int i = blockIdx.x * blockDim.x + threadIdx.x; i < N; i += stride) {
    float u   = su[i];
    float q1s = sq1[i];
    float q2s = sq2[i];
    int t0  = bin_of(u, umin, scale);
    int row = (int)(__float_as_uint(q1s) >> 31) * 2;   // sign bit = !correct
    atomicAdd(&hb[row * NB + t0],       fabsf(q1s));
    atomicAdd(&hb[(row + 1) * NB + t0], fabsf(q2s));
  }
  __syncthreads();
  for (int idx = threadIdx.x; idx < 4 * NB; idx += BS2) {
    float s = 0.f;
#pragma unroll
    for (int r = 0; r < NREP; ++r) s += h[r * RSTR + idx];
    partial2[idx * NBLK2 + blockIdx.x] = s;
  }
}

// Fallback: no stash space -> re-read probs, recompute everything.
__global__ __launch_bounds__(BS2) void pass2f_k(const float4* __restrict__ p4,
                                                const Accum* __restrict__ acc,
                                                float* __restrict__ partial2, int N) {
  __shared__ float h[NREP * RSTR];
  for (int k = threadIdx.x; k < NREP * RSTR; k += BS2) h[k] = 0.f;
  float umin, scale;
  reduce_minmax(acc, umin, scale);
  const int l0 = acc->l0;
  float* hb = &h[(threadIdx.x & (NREP - 1)) * RSTR];
  int stride = gridDim.x * blockDim.x;
  for (int i = blockIdx.x * blockDim.x + threadIdx.x; i < N; i += stride) {
    float4 a = p4[2 * i], b = p4[2 * i + 1];
    float p[8] = {a.x, a.y, a.z, a.w, b.x, b.y, b.z, b.w};
    float conf = p[0]; int pred = 0;
    float unc = 0.f;
#pragma unroll
    for (int j = 0; j < 8; ++j) {
      if (p[j] > conf) { conf = p[j]; pred = j; }
      unc -= p[j] * __logf(fmaxf(p[j], 1e-10f));
    }
    bool corr = (pred == l0);
    float tu = tanhf(unc);
    float base = corr ? conf : (1.f - conf);
    int t0 = bin_of(unc, umin, scale);
    int row = corr ? 0 : 2;
    atomicAdd(&hb[row * NB + t0],       base * (1.f - tu));
    atomicAdd(&hb[(row + 1) * NB + t0], base * tu);
  }
  __syncthreads();
  for (int idx = threadIdx.x; idx < 4 * NB; idx += BS2) {
    float s = 0.f;
#pragma unroll
    for (int r = 0; r < NREP; ++r) s += h[r * RSTR + idx];
    partial2[idx * NBLK2 + blockIdx.x] = s;
  }
}

__global__ __launch_bounds__(1024) void final_k(const float* __restrict__ partial2,
                                                const Accum* __restrict__ acc,
                                                float* __restrict__ out, int N) {
  __shared__ float hist[4 * NB];
  __shared__ double df[16], dc[16];
  __shared__ float sh_f, sh_c;
  int lane = threadIdx.x & 63, wid = threadIdx.x >> 6;  // 16 waves

  double f = 0.0, c = 0.0;
  for (int i = threadIdx.x; i < NBLK1; i += 1024) {
    f += (double)acc->f_part[i]; c += (double)acc->c_part[i];
  }
#pragma unroll
  for (int o = 32; o > 0; o >>= 1) { f += __shfl_down(f, o); c += __shfl_down(c, o); }
  if (lane == 0) { df[wid] = f; dc[wid] = c; }

  for (int cidx = wid; cidx < 4 * NB; cidx += 16) {
    float s = 0.f;
    for (int k = lane; k < NBLK2; k += 64) s += partial2[cidx * NBLK2 + k];
#pragma unroll
    for (int o = 32; o > 0; o >>= 1) s += __shfl_down(s, o);
    if (lane == 0) hist[cidx] = s;
  }
  __syncthreads();
  if (threadIdx.x == 0) {
    double ft = 0.0, ct = 0.0;
#pragma unroll
    for (int wv = 0; wv < 16; ++wv) { ft += df[wv]; ct += dc[wv]; }
    sh_f = (float)ft; sh_c = (float)ct;

    const float *hac = &hist[0], *hau = &hist[NB], *hic = &hist[2 * NB], *hiu = &hist[3 * NB];
    float tot_au = 0.f, tot_iu = 0.f;
    for (int s = 0; s < NB; ++s) { tot_au += hau[s]; tot_iu += hiu[s]; }
    float pac = 0.f, pau = 0.f, pic = 0.f, piu = 0.f, auc = 0.f, prev = 0.f;
    for (int t = 0; t < NTH; ++t) {
      pac += hac[t]; pau += hau[t]; pic += hic[t]; piu += hiu[t];
      float n_ac = pac, n_au = tot_au - pau, n_ic = pic, n_iu = tot_iu - piu;
      float avu = (n_ac + n_iu) / (n_ac + n_au + n_ic + n_iu + 1e-10f);
      if (t > 0) auc += 0.5f * (avu + prev) * 0.05f;
      prev = avu;
    }
    out[0] = -logf(auc + 1e-10f) + sh_f / (float)N;  // BETA = 1
    out[1] = sh_c / (float)N;
  }
}

extern "C" void kernel_launch(void* const* d_in, const int* in_sizes, int n_in,
                              void* d_out, int out_size, void* d_ws, size_t ws_size,
                              hipStream_t stream) {
  const float* probs = (const float*)d_in[0];
  const float* y     = (const float*)d_in[1];
  const float* w     = (const float*)d_in[2];
  float* out = (float*)d_out;
  int N = in_sizes[0] / C;

  Accum* acc = (Accum*)d_ws;
  size_t off_p2 = (sizeof(Accum) + 255) & ~(size_t)255;
  size_t off_su = (off_p2 + (size_t)(4 * NB) * NBLK2 * sizeof(float) + 255) & ~(size_t)255;
  size_t one    = ((size_t)N * sizeof(float) + 255) & ~(size_t)255;
  size_t need   = off_su + 3 * one;
  float* partial2 = (float*)((char*)d_ws + off_p2);
  float* su  = (float*)((char*)d_ws + off_su);
  float* sq1 = (float*)((char*)d_ws + off_su + one);
  float* sq2 = (float*)((char*)d_ws + off_su + 2 * one);

  if (ws_size >= need) {
    pass1_k<true><<<NBLK1, BS1, 0, stream>>>((const float4*)probs, (const float4*)y,
                                             (const float4*)w, y, acc, su, sq1, sq2, N);
    pass2_k<<<NBLK2, BS2, 0, stream>>>(su, sq1, sq2, acc, partial2, N);
  } else {
    pass1_k<false><<<NBLK1, BS1, 0, stream>>>((const float4*)probs, (const float4*)y,
                                              (const float4*)w, y, acc,
                                              nullptr, nullptr, nullptr, N);
    pass2f_k<<<NBLK2, BS2, 0, stream>>>((const float4*)probs, acc, partial2, N);
  }
  final_k<<<1, 1024, 0, stream>>>(partial2, acc, out, N);
}